// Round 1
// baseline (435.824 us; speedup 1.0000x reference)
//
#include <hip/hip_runtime.h>
#include <math.h>

// FourierLinear: rfft2 -> select 415 low modes -> per-mode 32x32 complex mix -> irfft2
// B=16, N=256 pixels, C_in=C_out=32, modes: |fy|<=16 (33 rows: idx 0..16,240..255), fx idx 0..16 (17 cols)
//
// Pipeline (all partial DFTs, fp32 VALU, twiddle recurrences in registers):
//  k_fwd_x : x (B,256,256,32) f32 -> S1 (B,256,17,32) c64   [partial rfft over x]
//  k_fwd_y : S1 -> S2 (B,33,17,32) c64                      [partial fft over y at 33 ky rows]
//  k_zero  : Y = 0
//  k_mix   : Y[b,j,k,o] = sum_i S2[b,j,k,i] * (w_re+i w_im)[f,i,o]  (scatter by mode)
//  k_inv_y : Y -> T (B,256,17,32) c64                       [inverse fft over y, unscaled]
//  k_inv_x : T -> out (B,256,256,32) f32                    [irfft over x, scale 1/65536]

#define PI_F 3.14159265358979323846f

__device__ __forceinline__ float2 cmul(float2 a, float2 b) {
  return make_float2(a.x * b.x - a.y * b.y, a.x * b.y + a.y * b.x);
}

// ---------------- Stage 1: partial rfft along x (k = 0..16) ----------------
// grid 512, block 256: 8 (b,y)-rows per block, 32 channels per row-slot.
__global__ __launch_bounds__(256) void k_fwd_x(const float* __restrict__ x,
                                               float2* __restrict__ S1) {
  __shared__ float2 tw[256];  // e^{-i 2 pi t / 256}
  int t = threadIdx.x;
  {
    float s, c;
    sincosf(-2.0f * PI_F * (float)t / 256.0f, &s, &c);
    tw[t] = make_float2(c, s);
  }
  __syncthreads();
  int c = t & 31;
  int slot = t >> 5;
  size_t row = (size_t)blockIdx.x * 8 + slot;  // b*256 + y
  const float* xp = x + row * (256 * 32) + c;
  float2 acc[17];
#pragma unroll
  for (int k = 0; k < 17; ++k) acc[k] = make_float2(0.f, 0.f);
  {
    float v0 = xp[0];
    float v128 = xp[128 * 32];
#pragma unroll
    for (int k = 0; k < 17; ++k) acc[k].x += v0 + ((k & 1) ? -v128 : v128);
  }
  for (int xx = 1; xx <= 127; ++xx) {
    float va = xp[xx * 32];
    float vb = xp[(256 - xx) * 32];
    float p = va + vb;   // even part -> cos
    float m = va - vb;   // odd part  -> sin
    float2 step = tw[xx];
    float2 w = step;     // w = e^{-i theta k x}, starting at k=1
    acc[0].x += p;
#pragma unroll
    for (int k = 1; k < 17; ++k) {
      acc[k].x = fmaf(p, w.x, acc[k].x);   // re += p*cos
      acc[k].y = fmaf(m, w.y, acc[k].y);   // im += m*(-sin) = -m*sin
      w = cmul(w, step);
    }
  }
  float2* op = S1 + row * (17 * 32) + c;
#pragma unroll
  for (int k = 0; k < 17; ++k) op[k * 32] = acc[k];
}

// ---------------- Stage 2: partial complex fft along y (33 ky rows) ----------------
// grid 16*17 = 272 blocks (b,k), block 256.
__global__ __launch_bounds__(256) void k_fwd_y(const float2* __restrict__ S1,
                                               float2* __restrict__ S2) {
  __shared__ float2 V[256][32];  // [y][c]
  int t = threadIdx.x;
  int b = blockIdx.x / 17;
  int k = blockIdx.x % 17;
  int c = t & 31;
  int ys = t >> 5;
  const float2* sp = S1 + ((size_t)b * 256 * 17 + k) * 32 + c;
  for (int y = ys; y < 256; y += 8) V[y][c] = sp[(size_t)y * 17 * 32];
  __syncthreads();
  for (int item = t; item < 33 * 32; item += 256) {
    int j = item >> 5;
    int cc = item & 31;
    int ky = (j < 17) ? j : j + 223;  // 0..16, 240..255
    float s, cs;
    sincosf(-2.0f * PI_F * (float)ky / 256.0f, &s, &cs);
    float2 step = make_float2(cs, s);
    float2 w = make_float2(1.f, 0.f);
    float2 a = make_float2(0.f, 0.f);
    for (int y = 0; y < 256; ++y) {
      float2 v = V[y][cc];
      a.x += v.x * w.x - v.y * w.y;
      a.y += v.x * w.y + v.y * w.x;
      w = cmul(w, step);
    }
    S2[(((size_t)b * 33 + j) * 17 + k) * 32 + cc] = a;
  }
}

// ---------------- zero-fill the scattered mode tensor ----------------
__global__ void k_zero(float4* __restrict__ p, int n) {
  int i = blockIdx.x * blockDim.x + threadIdx.x;
  if (i < n) p[i] = make_float4(0.f, 0.f, 0.f, 0.f);
}

// ---------------- Stage 3: per-mode complex channel mix ----------------
// grid m (=415) blocks, block 256.
__global__ __launch_bounds__(256) void k_mix(const float* __restrict__ wre,
                                             const float* __restrict__ wim,
                                             const int* __restrict__ idx0,
                                             const int* __restrict__ idx1,
                                             const float2* __restrict__ S2,
                                             float2* __restrict__ Yb) {
  __shared__ float2 wl[32][32];  // [i][o]
  __shared__ float2 xl[16][32];  // [b][i]
  int f = blockIdx.x;
  int t = threadIdx.x;
  int i0 = idx0[f];
  int k = idx1[f];
  int j = (i0 < 17) ? i0 : i0 - 223;
  const float* wr = wre + (size_t)f * 1024;
  const float* wi = wim + (size_t)f * 1024;
  for (int q = t; q < 1024; q += 256)
    wl[q >> 5][q & 31] = make_float2(wr[q], wi[q]);
  for (int q = t; q < 512; q += 256) {
    int b = q >> 5, i = q & 31;
    xl[b][i] = S2[(((size_t)b * 33 + j) * 17 + k) * 32 + i];
  }
  __syncthreads();
  for (int q = t; q < 512; q += 256) {
    int b = q >> 5, o = q & 31;
    float2 a = make_float2(0.f, 0.f);
#pragma unroll
    for (int i = 0; i < 32; ++i) {
      float2 xv = xl[b][i];
      float2 wv = wl[i][o];
      a.x += xv.x * wv.x - xv.y * wv.y;
      a.y += xv.x * wv.y + xv.y * wv.x;
    }
    Yb[(((size_t)b * 33 + j) * 17 + k) * 32 + o] = a;
  }
}

// ---------------- Stage 4A: inverse complex fft along y (unscaled) ----------------
// grid 272 blocks (b,k), block 256. ky iterated in contiguous order 240..255,0..16.
__global__ __launch_bounds__(256) void k_inv_y(const float2* __restrict__ Yb,
                                               float2* __restrict__ T) {
  __shared__ float2 Yl[33][32];  // reordered: jp=0 -> ky=240 ... jp=32 -> ky=16
  int t = threadIdx.x;
  int b = blockIdx.x / 17;
  int k = blockIdx.x % 17;
  for (int q = t; q < 33 * 32; q += 256) {
    int j = q >> 5, cc = q & 31;
    int jp = (j < 17) ? j + 16 : j - 17;
    Yl[jp][cc] = Yb[(((size_t)b * 33 + j) * 17 + k) * 32 + cc];
  }
  __syncthreads();
  for (int item = t; item < 256 * 32; item += 256) {
    int y = item >> 5;
    int cc = item & 31;
    float s0, c0;
    sincosf(2.0f * PI_F * (float)((240 * y) & 255) / 256.0f, &s0, &c0);
    float ss, cs;
    sincosf(2.0f * PI_F * (float)y / 256.0f, &ss, &cs);
    float2 w = make_float2(c0, s0);     // e^{+i 2 pi * 240*y / 256}
    float2 step = make_float2(cs, ss);  // e^{+i 2 pi * y / 256}
    float2 a = make_float2(0.f, 0.f);
#pragma unroll 11
    for (int jp = 0; jp < 33; ++jp) {
      float2 v = Yl[jp][cc];
      a.x += v.x * w.x - v.y * w.y;
      a.y += v.x * w.y + v.y * w.x;
      w = cmul(w, step);
    }
    T[((size_t)(b * 256 + y) * 17 + k) * 32 + cc] = a;
  }
}

// ---------------- Stage 4B: partial irfft along x, scale 1/65536 ----------------
// grid 512, block 256: 8 rows per block. numpy c2r semantics: Im(bin 0) ignored.
__global__ __launch_bounds__(256) void k_inv_x(const float2* __restrict__ T,
                                               float* __restrict__ out) {
  __shared__ float2 tw[256];  // e^{+i 2 pi t/256}
  int t = threadIdx.x;
  {
    float s, c;
    sincosf(2.0f * PI_F * (float)t / 256.0f, &s, &c);
    tw[t] = make_float2(c, s);
  }
  __syncthreads();
  int c = t & 31;
  int slot = t >> 5;
  size_t row = (size_t)blockIdx.x * 8 + slot;  // b*256 + y
  const float2* tp = T + row * (17 * 32) + c;
  float2 Tr[17];
#pragma unroll
  for (int k = 0; k < 17; ++k) Tr[k] = tp[k * 32];
  const float sc = 1.0f / 65536.0f;
  float sum_all = 0.f, sum_alt = 0.f;
#pragma unroll
  for (int k = 1; k < 17; ++k) {
    sum_all += Tr[k].x;
    sum_alt += (k & 1) ? -Tr[k].x : Tr[k].x;
  }
  float* op = out + row * (256 * 32) + c;
  op[0] = sc * (Tr[0].x + 2.f * sum_all);
  op[128 * 32] = sc * (Tr[0].x + 2.f * sum_alt);
  for (int xx = 1; xx <= 127; ++xx) {
    float2 step = tw[xx];
    float2 w = step;
    float A = 0.f, Bv = 0.f;
#pragma unroll
    for (int k = 1; k < 17; ++k) {
      A = fmaf(Tr[k].x, w.x, A);    // sum re_k * cos
      Bv = fmaf(Tr[k].y, w.y, Bv);  // sum im_k * sin
      w = cmul(w, step);
    }
    op[xx * 32] = sc * (Tr[0].x + 2.f * (A - Bv));
    op[(256 - xx) * 32] = sc * (Tr[0].x + 2.f * (A + Bv));
  }
}

extern "C" void kernel_launch(void* const* d_in, const int* in_sizes, int n_in,
                              void* d_out, int out_size, void* d_ws, size_t ws_size,
                              hipStream_t stream) {
  const float* x = (const float*)d_in[0];
  const float* wre = (const float*)d_in[1];
  const float* wim = (const float*)d_in[2];
  const int* idx0 = (const int*)d_in[3];
  const int* idx1 = (const int*)d_in[4];
  float* out = (float*)d_out;
  int m = in_sizes[1] / 1024;  // number of modes (415)

  // workspace layout (bytes):
  //   S1: 16*256*17*32 * 8 = 17,825,792
  //   S2: 16*33*17*32  * 8 =  2,297,856
  //   Y : 16*33*17*32  * 8 =  2,297,856
  //   T : aliases S1 (S1 dead after k_fwd_y)
  char* ws = (char*)d_ws;
  float2* S1 = (float2*)(ws);
  float2* S2 = (float2*)(ws + 17825792);
  float2* Yb = (float2*)(ws + 20123648);
  float2* T = (float2*)(ws);  // alias S1

  k_fwd_x<<<512, 256, 0, stream>>>(x, S1);
  k_fwd_y<<<16 * 17, 256, 0, stream>>>(S1, S2);
  {
    int n4 = (int)(2297856 / 16);  // float4 count
    k_zero<<<(n4 + 255) / 256, 256, 0, stream>>>((float4*)Yb, n4);
  }
  k_mix<<<m, 256, 0, stream>>>(wre, wim, idx0, idx1, S2, Yb);
  k_inv_y<<<16 * 17, 256, 0, stream>>>(Yb, T);
  k_inv_x<<<512, 256, 0, stream>>>(T, out);
}